// Round 4
// baseline (98.701 us; speedup 1.0000x reference)
//
#include <hip/hip_runtime.h>

// N = 8192 rows, D = 512 features.
// loss = mean((1-cos)^2) over all pairs (margin=1 makes labels irrelevant:
//        max(1-cos,0)^2 == (1-cos)^2 since cos <= 1).
// N^2*loss = N^2 - 2*||s||^2 + ||Xn^T Xn||_F^2,  s_a = sum_i xn[i][a].
// G = Xn^T Xn is 512x512 symmetric -> 136 upper-triangle 32x32 tiles,
// off-diagonal tiles weighted 2 in the Frobenius sum.

typedef __attribute__((ext_vector_type(8))) short  s8;      // 8 bf16 payload
typedef __attribute__((ext_vector_type(8))) __bf16 bf8;     // mfma operand
typedef __attribute__((ext_vector_type(4))) float  f4;
typedef __attribute__((ext_vector_type(4))) unsigned short u4v;

#define NT32 136                 // 16*17/2 upper-triangle 32x32 tiles
#define KOUT 16                  // K splits
#define KCW  512                 // 8192 / KOUT per block

// ws layout (bytes)
#define OFF_XT  0u                               // bf16 xt[512][8192] = 8 MiB
#define OFF_INV (8u * 1024u * 1024u)             // f32 inv[8192]
#define OFF_S   (OFF_INV + 8192u * 4u)           // f32 svec[512]
#define OFF_S2  (OFF_S + 512u * 4u)              // f32 s2[1]
#define OFF_TK  (OFF_S2 + 4u)                    // int ticket[1]
#define OFF_GP  (OFF_S2 + 64u)                   // f32 gp[KOUT][NT32][1024] = 8.9 MiB

__device__ __forceinline__ unsigned short f2bf(float f) {
    union { float f; unsigned u; } v; v.f = f;
    unsigned r = v.u + 0x7FFFu + ((v.u >> 16) & 1u);   // RNE
    return (unsigned short)(r >> 16);
}

// --- K1a: per-row inv-norms (one wave/row) + zero svec/s2/ticket from blk 0 ---
__global__ __launch_bounds__(256) void k_norms(
    const float* __restrict__ reps, float* __restrict__ inv,
    float* __restrict__ zbuf /* svec[512] + s2 + ticket contiguous */)
{
    const int t = threadIdx.x, lane = t & 63, w = t >> 6;
    if (blockIdx.x == 0) {
        for (int z = t; z < 514; z += 256) zbuf[z] = 0.f;
    }
    const int row = blockIdx.x * 4 + w;
    const float4 x0 = *(const float4*)(reps + (size_t)row * 512 + lane * 4);
    const float4 x1 = *(const float4*)(reps + (size_t)row * 512 + 256 + lane * 4);
    float ss = x0.x*x0.x + x0.y*x0.y + x0.z*x0.z + x0.w*x0.w
             + x1.x*x1.x + x1.y*x1.y + x1.z*x1.z + x1.w*x1.w;
    #pragma unroll
    for (int off = 1; off < 64; off <<= 1) ss += __shfl_xor(ss, off, 64);
    if (lane == 0) inv[row] = 1.0f / fmaxf(sqrtf(ss), 1e-8f);
}

// --- K1b: normalize + bf16 + 64x64 transpose tiles + fused s-vector ---
__global__ __launch_bounds__(256) void k_norm_transpose(
    const float* __restrict__ reps, const float* __restrict__ inv,
    unsigned short* __restrict__ xt, float* __restrict__ svec)
{
    __shared__ unsigned short tile[64][72];     // +8 pad
    __shared__ float sred[4][64];
    const int t = threadIdx.x, lane = t & 63, w = t >> 6;
    const int a0 = blockIdx.x * 64, i0 = blockIdx.y * 64;
    const int colg = t & 15;                    // col group: cols colg*4..+3
    const int ig0  = t >> 4;                    // 0..15

    float4 sa = {0.f, 0.f, 0.f, 0.f};
    #pragma unroll
    for (int j = 0; j < 4; ++j) {
        const int il = ig0 + j * 16;
        const float iv = inv[i0 + il];
        const float4 x = *(const float4*)(reps + (size_t)(i0 + il) * 512 + a0 + colg * 4);
        const float4 xn = {x.x * iv, x.y * iv, x.z * iv, x.w * iv};
        sa.x += xn.x; sa.y += xn.y; sa.z += xn.z; sa.w += xn.w;
        ushort4 p;
        p.x = f2bf(xn.x); p.y = f2bf(xn.y); p.z = f2bf(xn.z); p.w = f2bf(xn.w);
        *(ushort4*)&tile[il][colg * 4] = p;
    }
    __syncthreads();

    // register 4x4 sub-block transpose -> coalesced xt writes
    {
        const int ig = t & 15, ag = t >> 4;
        u4v rows[4];
        #pragma unroll
        for (int r = 0; r < 4; ++r)
            rows[r] = *(const u4v*)&tile[ig * 4 + r][ag * 4];
        #pragma unroll
        for (int j = 0; j < 4; ++j) {
            ushort4 o;
            o.x = (unsigned short)rows[0][j];
            o.y = (unsigned short)rows[1][j];
            o.z = (unsigned short)rows[2][j];
            o.w = (unsigned short)rows[3][j];
            *(ushort4*)(xt + (size_t)(a0 + ag * 4 + j) * 8192 + i0 + ig * 4) = o;
        }
    }

    // s-vector: reduce over 16 i-groups (in-wave via shfl, cross-wave via LDS)
    sa.x += __shfl_xor(sa.x, 16, 64); sa.x += __shfl_xor(sa.x, 32, 64);
    sa.y += __shfl_xor(sa.y, 16, 64); sa.y += __shfl_xor(sa.y, 32, 64);
    sa.z += __shfl_xor(sa.z, 16, 64); sa.z += __shfl_xor(sa.z, 32, 64);
    sa.w += __shfl_xor(sa.w, 16, 64); sa.w += __shfl_xor(sa.w, 32, 64);
    if (lane < 16) {
        sred[w][lane * 4 + 0] = sa.x; sred[w][lane * 4 + 1] = sa.y;
        sred[w][lane * 4 + 2] = sa.z; sred[w][lane * 4 + 3] = sa.w;
    }
    __syncthreads();
    if (t < 64) {
        const float v = sred[0][t] + sred[1][t] + sred[2][t] + sred[3][t];
        atomicAdd(&svec[a0 + t], v);
    }
}

// --- K2: partial Gram, 32x32 upper-tri tiles; 1 wave = 1 tile-slice ---
__global__ __launch_bounds__(64) void k_gram(
    const unsigned short* __restrict__ xt, float* __restrict__ gp)
{
    const int lane = threadIdx.x;
    const int l15 = lane & 15, l4 = lane >> 4;
    int tt = blockIdx.x, ta = 0;
    while (tt >= 16 - ta) { tt -= 16 - ta; ++ta; }
    const int tb = ta + tt;
    const int k0 = blockIdx.y * KCW;
    const unsigned short* Arow = xt + (size_t)(ta * 32 + l15) * 8192;
    const unsigned short* Brow = xt + (size_t)(tb * 32 + l15) * 8192;

    f4 acc[2][2];
    #pragma unroll
    for (int mi = 0; mi < 2; ++mi)
        #pragma unroll
        for (int ni = 0; ni < 2; ++ni) {
            f4 z = {0.f, 0.f, 0.f, 0.f};
            acc[mi][ni] = z;
        }

    for (int k = 0; k < KCW; k += 32) {
        const int ko = k0 + k + l4 * 8;
        s8 af[2], bfr[2];
        af[0]  = *(const s8*)(Arow + ko);
        af[1]  = *(const s8*)(Arow + (size_t)16 * 8192 + ko);
        bfr[0] = *(const s8*)(Brow + ko);
        bfr[1] = *(const s8*)(Brow + (size_t)16 * 8192 + ko);
        #pragma unroll
        for (int mi = 0; mi < 2; ++mi)
            #pragma unroll
            for (int ni = 0; ni < 2; ++ni)
                acc[mi][ni] = __builtin_amdgcn_mfma_f32_16x16x32_bf16(
                    __builtin_bit_cast(bf8, af[mi]),
                    __builtin_bit_cast(bf8, bfr[ni]),
                    acc[mi][ni], 0, 0, 0);
    }

    float* gb = gp + ((size_t)blockIdx.y * NT32 + blockIdx.x) * 1024;
    #pragma unroll
    for (int mi = 0; mi < 2; ++mi)
        #pragma unroll
        for (int ni = 0; ni < 2; ++ni)
            #pragma unroll
            for (int r = 0; r < 4; ++r) {
                const int a_ = mi * 16 + l4 * 4 + r;   // C/D: row=(l>>4)*4+r
                const int b_ = ni * 16 + l15;          //      col=l&15
                gb[a_ * 32 + b_] = acc[mi][ni][r];
            }
}

// --- K3: S2 = sum wgt*(sum over KOUT partials)^2, then last block finishes ---
__global__ __launch_bounds__(256) void k_reduce_final(
    const float* __restrict__ gp, const float* __restrict__ svec,
    float* __restrict__ s2, int* __restrict__ ticket,
    float* __restrict__ out)
{
    __shared__ float part[4];
    __shared__ int lastFlag;
    const int t = threadIdx.x;
    const int c = blockIdx.x * 256 + t;              // f4 cell, 34816 total
    const f4* g4 = (const f4*)gp;
    f4 s = {0.f, 0.f, 0.f, 0.f};
    #pragma unroll
    for (int p = 0; p < KOUT; ++p) s += g4[(size_t)p * (NT32 * 256) + c];
    int tt = c >> 8, ta = 0;                         // 256 f4 per tile plane
    while (tt >= 16 - ta) { tt -= 16 - ta; ++ta; }
    const float wgt = (tt == 0) ? 1.f : 2.f;         // diag vs off-diag tile
    float sq = wgt * (s.x * s.x + s.y * s.y + s.z * s.z + s.w * s.w);
    #pragma unroll
    for (int off = 1; off < 64; off <<= 1) sq += __shfl_xor(sq, off, 64);
    if ((t & 63) == 0) part[t >> 6] = sq;
    __syncthreads();
    if (t == 0) {
        atomicAdd(s2, part[0] + part[1] + part[2] + part[3]);
        __threadfence();
        lastFlag = (atomicAdd(ticket, 1) == (int)gridDim.x - 1);
    }
    __syncthreads();
    if (lastFlag) {                                  // block-uniform
        __threadfence();
        const float v0 = svec[t], v1 = svec[t + 256];
        float p = v0 * v0 + v1 * v1;
        #pragma unroll
        for (int off = 1; off < 64; off <<= 1) p += __shfl_xor(p, off, 64);
        if ((t & 63) == 0) part[t >> 6] = p;
        __syncthreads();
        if (t == 0) {
            const float s1 = part[0] + part[1] + part[2] + part[3];
            const float S2 = atomicAdd(s2, 0.f);     // read accumulated total
            const double NN = 67108864.0;            // 8192^2
            out[0] = (float)((NN - 2.0 * (double)s1 + (double)S2) / NN);
        }
    }
}

extern "C" void kernel_launch(void* const* d_in, const int* in_sizes, int n_in,
                              void* d_out, int out_size, void* d_ws, size_t ws_size,
                              hipStream_t stream)
{
    const float* reps = (const float*)d_in[0];
    // d_in[1] (labels) is mathematically irrelevant for margin = 1.0.
    char* ws = (char*)d_ws;
    unsigned short* xt   = (unsigned short*)(ws + OFF_XT);
    float*          invn = (float*)(ws + OFF_INV);
    float*          svec = (float*)(ws + OFF_S);
    float*          s2   = (float*)(ws + OFF_S2);
    int*            tick = (int*)(ws + OFF_TK);
    float*          gp   = (float*)(ws + OFF_GP);

    k_norms<<<2048, 256, 0, stream>>>(reps, invn, svec);
    k_norm_transpose<<<dim3(8, 128), 256, 0, stream>>>(reps, invn, xt, svec);
    k_gram<<<dim3(NT32, KOUT), 64, 0, stream>>>(xt, gp);
    k_reduce_final<<<NT32, 256, 0, stream>>>(gp, svec, s2, tick, (float*)d_out);
}